// Round 9
// baseline (322.001 us; speedup 1.0000x reference)
//
#include <hip/hip_runtime.h>

// LearnPermutations: K=256 independent 256x256 Sinkhorn normalizations.
// One 1024-thread block per matrix; matrix register-resident (8x8/thread as
// packed float2). Row pass in log2 domain (in-wave only), then linear
// scaling-vector Sinkhorn u = rcp(A v), v = rcp(A^T u) with ONE barrier per
// iteration: column sums accumulate via LDS atomicAdd (ds_add_f32) into a
// 3-buffer rotation (add/read/zero), so no reduction tree and no second
// barrier. Epilogue: out = a_ij * u_i * v_j.

#define KMAT 256

typedef float f2 __attribute__((ext_vector_type(2)));
typedef unsigned uint2_ev __attribute__((ext_vector_type(2)));

__device__ __forceinline__ float fast_exp2(float x) {
#if __has_builtin(__builtin_amdgcn_exp2f)
  return __builtin_amdgcn_exp2f(x);
#else
  return exp2f(x);
#endif
}

__device__ __forceinline__ float fast_log2(float x) {
#if __has_builtin(__builtin_amdgcn_logf)
  return __builtin_amdgcn_logf(x);
#else
  return __log2f(x);
#endif
}

__device__ __forceinline__ float fast_rcp(float x) {
#if __has_builtin(__builtin_amdgcn_rcpf)
  return __builtin_amdgcn_rcpf(x);
#else
  return 1.0f / x;
#endif
}

__device__ __forceinline__ f2 f2fma(f2 a, f2 b, f2 c) {
#if __has_builtin(__builtin_elementwise_fma)
  return __builtin_elementwise_fma(a, b, c);
#else
  f2 r; r[0] = fmaf(a[0], b[0], c[0]); r[1] = fmaf(a[1], b[1], c[1]); return r;
#endif
}

template <int CTRL>
__device__ __forceinline__ float dpp_movf(float x) {
  return __int_as_float(
      __builtin_amdgcn_update_dpp(0, __float_as_int(x), CTRL, 0xf, 0xf, true));
}

__device__ __forceinline__ uint2_ev pl16_swap(unsigned a, unsigned b) {
  return __builtin_amdgcn_permlane16_swap(a, b, false, false);
}

// 32-lane half-group reductions (verified construction, R1-R8).
__device__ __forceinline__ float hgroup_max(float x) {
  x = fmaxf(x, dpp_movf<0x121>(x));
  x = fmaxf(x, dpp_movf<0x122>(x));
  x = fmaxf(x, dpp_movf<0x124>(x));
  x = fmaxf(x, dpp_movf<0x128>(x));
  uint2_ev r = pl16_swap(__float_as_uint(x), __float_as_uint(x));
  return fmaxf(__uint_as_float(r[0]), __uint_as_float(r[1]));
}

__device__ __forceinline__ float hgroup_sum(float x) {
  x += dpp_movf<0x121>(x);
  x += dpp_movf<0x122>(x);
  x += dpp_movf<0x124>(x);
  x += dpp_movf<0x128>(x);
  uint2_ev r = pl16_swap(__float_as_uint(x), __float_as_uint(x));
  return __uint_as_float(r[0]) + __uint_as_float(r[1]);
}

// Gumbel noise + temperature scaling, output in log2 domain.
__device__ __forceinline__ float gumbel_la(float p, float uv, float scale) {
  float lnu = fast_log2(uv + 1e-20f) * 0.69314718056f;
  float g = fast_log2(1e-20f - lnu) * (-0.0069314718056f);
  return (p + g) * scale;
}

__global__ __launch_bounds__(1024)
__attribute__((amdgpu_waves_per_eu(4, 4)))
void lp_sinkhorn_kernel(
    const float* __restrict__ plw, const float* __restrict__ uin,
    const int* __restrict__ itp, float* __restrict__ out) {
  const int k = blockIdx.x;
  const int t = threadIdx.x;
  const int br = t >> 5;   // 0..31 : half-wave row-group (8 rows each)
  const int bc = t & 31;   // 0..31 : col-group (8 cols each)

  // Column pair (8bc+2p, 8bc+2p+1) lives at f2-slot 32p+bc.
  // Three rotating colsum buffers: A=atomic-add target (iter k), R=read
  // (holds colsums of iter k-1), Z=zeroed for iter k+1.
  __shared__ f2 cbuf[3][128];

  // init: zero the epoch-1 add target (cbuf[1]); others zeroed in-rotation.
  if (t < 128) cbuf[1][t] = f2{0.f, 0.f};

  // ---- schedule parameters from `iterations` (uniform) ----
  double frac = (double)itp[0] * 1e-5;
  frac = frac < 0.0 ? 0.0 : (frac > 1.0 ? 1.0 : frac);
  const int n_iters = (int)(20.0 + frac * 130.0);
  const float tauf = (float)exp2((-3.0 - 4.0 * frac) * 3.3219280948873623);
  const float scale = (float)(1.4426950408889634 / (double)tauf);

  f2 la[8][4];

  // ---- load + gumbel + scale (log2 domain) ----
  const float4* p4 = (const float4*)plw + k * 16384;
  const float4* u4 = (const float4*)uin + k * 16384;
#pragma unroll
  for (int i = 0; i < 8; ++i) {
    const int ridx = ((br << 3) + i) * 64 + (bc << 1);
    float4 p0 = p4[ridx];
    float4 p1 = p4[ridx + 1];
    float4 v0 = u4[ridx];
    float4 v1 = u4[ridx + 1];
    la[i][0] = f2{gumbel_la(p0.x, v0.x, scale), gumbel_la(p0.y, v0.y, scale)};
    la[i][1] = f2{gumbel_la(p0.z, v0.z, scale), gumbel_la(p0.w, v0.w, scale)};
    la[i][2] = f2{gumbel_la(p1.x, v1.x, scale), gumbel_la(p1.y, v1.y, scale)};
    la[i][3] = f2{gumbel_la(p1.z, v1.z, scale), gumbel_la(p1.w, v1.w, scale)};
  }

  // ---- row pass #1 (log domain, in-wave) + in-place convert to linear ----
  // After this, la is linear with rowsums == 1.
#pragma unroll
  for (int i = 0; i < 8; ++i) {
    float m = fmaxf(la[i][0][0], la[i][0][1]);
#pragma unroll
    for (int p = 1; p < 4; ++p) m = fmaxf(m, fmaxf(la[i][p][0], la[i][p][1]));
    m = hgroup_max(m);
    float s = 0.f;
#pragma unroll
    for (int p = 0; p < 4; ++p) {
      la[i][p] = f2{fast_exp2(la[i][p][0] - m), fast_exp2(la[i][p][1] - m)};
      s += la[i][p][0] + la[i][p][1];
    }
    s = hgroup_sum(s);
    const float r = fast_rcp(s);
#pragma unroll
    for (int p = 0; p < 4; ++p) la[i][p] *= f2{r, r};
  }

  // barrier: init-zero of cbuf[1] must precede epoch-1 atomics
  __syncthreads();

  f2* Ca = cbuf[1];  // add target
  f2* Cr = cbuf[0];  // read source (prev colsums)
  f2* Cz = cbuf[2];  // zero for next epoch
  float u[8] = {1.f, 1.f, 1.f, 1.f, 1.f, 1.f, 1.f, 1.f};

  // ---- epoch 1: col sums of row-normalized A (u == 1) ----
  {
    f2 cs[4];
#pragma unroll
    for (int p = 0; p < 4; ++p) cs[p] = la[0][p];
#pragma unroll
    for (int i = 1; i < 8; ++i)
#pragma unroll
      for (int p = 0; p < 4; ++p) cs[p] += la[i][p];
    float* CaF = (float*)Ca;
#pragma unroll
    for (int p = 0; p < 4; ++p) {
      atomicAdd(&CaF[64 * p + 2 * bc], cs[p][0]);
      atomicAdd(&CaF[64 * p + 2 * bc + 1], cs[p][1]);
    }
    if (t < 128) Cz[t] = f2{0.f, 0.f};
    __syncthreads();
    f2* tmp = Ca; Ca = Cz; Cz = Cr; Cr = tmp;  // (A,R,Z) <- (Z,A,R)
  }

  // ---- epochs 2..n: u = rcp(A v); colsums of a*u via atomics ----
  for (int it = 2; it <= n_iters; ++it) {
    f2 v2[4];
#pragma unroll
    for (int p = 0; p < 4; ++p) {
      const f2 c = Cr[32 * p + bc];
      v2[p] = f2{fast_rcp(c[0]), fast_rcp(c[1])};
    }
    // phase A: row dots (packed) + in-wave reduce
#pragma unroll
    for (int i = 0; i < 8; ++i) {
      f2 a01 = la[i][0] * v2[0];
      a01 = f2fma(la[i][1], v2[1], a01);
      f2 a23 = la[i][2] * v2[2];
      a23 = f2fma(la[i][3], v2[3], a23);
      f2 acc = a01 + a23;
      u[i] = fast_rcp(hgroup_sum(acc[0] + acc[1]));
    }
    // phase B: col partials (packed fma) -> atomic accumulate
    f2 cs[4];
    {
      const f2 ub0 = f2{u[0], u[0]};
#pragma unroll
      for (int p = 0; p < 4; ++p) cs[p] = la[0][p] * ub0;
    }
#pragma unroll
    for (int i = 1; i < 8; ++i) {
      const f2 ub = f2{u[i], u[i]};
#pragma unroll
      for (int p = 0; p < 4; ++p) cs[p] = f2fma(la[i][p], ub, cs[p]);
    }
    float* CaF = (float*)Ca;
#pragma unroll
    for (int p = 0; p < 4; ++p) {
      atomicAdd(&CaF[64 * p + 2 * bc], cs[p][0]);
      atomicAdd(&CaF[64 * p + 2 * bc + 1], cs[p][1]);
    }
    if (t < 128) Cz[t] = f2{0.f, 0.f};
    __syncthreads();
    f2* tmp = Ca; Ca = Cz; Cz = Cr; Cr = tmp;
  }

  // ---- epilogue: v = rcp(last colsums); out = a_ij * u_i * v_j ----
  f2 v2[4];
#pragma unroll
  for (int p = 0; p < 4; ++p) {
    const f2 c = Cr[32 * p + bc];
    v2[p] = f2{fast_rcp(c[0]), fast_rcp(c[1])};
  }
  float4* o4 = (float4*)out + k * 16384;
#pragma unroll
  for (int i = 0; i < 8; ++i) {
    const int ridx = ((br << 3) + i) * 64 + (bc << 1);
    const f2 ub = f2{u[i], u[i]};
    f2 r0 = (la[i][0] * ub) * v2[0];
    f2 r1 = (la[i][1] * ub) * v2[1];
    f2 r2 = (la[i][2] * ub) * v2[2];
    f2 r3 = (la[i][3] * ub) * v2[3];
    float4 a, b;
    a.x = r0[0]; a.y = r0[1]; a.z = r1[0]; a.w = r1[1];
    b.x = r2[0]; b.y = r2[1]; b.z = r3[0]; b.w = r3[1];
    o4[ridx] = a;
    o4[ridx + 1] = b;
  }
}

extern "C" void kernel_launch(void* const* d_in, const int* in_sizes, int n_in,
                              void* d_out, int out_size, void* d_ws,
                              size_t ws_size, hipStream_t stream) {
  const float* plw = (const float*)d_in[0];
  const float* u = (const float*)d_in[1];
  const int* iters = (const int*)d_in[2];
  float* out = (float*)d_out;
  (void)in_sizes; (void)n_in; (void)out_size; (void)d_ws; (void)ws_size;
  lp_sinkhorn_kernel<<<dim3(KMAT), dim3(1024), 0, stream>>>(plw, u, iters, out);
}

// Round 10
// 82.910 us; speedup vs baseline: 3.8837x; 3.8837x over previous
//
#include <hip/hip_runtime.h>

// LearnPermutations: K=256 independent 256x256 Sinkhorn normalizations.
// One 1024-thread block per matrix; matrix register-resident (8x8/thread as
// packed float2). In-wave log2-domain row pass #1 (fused exp2) -> linear
// matrix with rowsums==1; then n_iters column epochs of scaling-vector
// Sinkhorn (epoch 1: u==1). Per epoch: ONE LDS round-trip with wave-combined
// partials (permlane32) + shallow 4-read quad-DPP tree, two barriers.
// Epilogue: out = a_ij * u_i * v_j.

#define KMAT 256

typedef float f2 __attribute__((ext_vector_type(2)));
typedef unsigned uint2_ev __attribute__((ext_vector_type(2)));

__device__ __forceinline__ float fast_exp2(float x) {
#if __has_builtin(__builtin_amdgcn_exp2f)
  return __builtin_amdgcn_exp2f(x);
#else
  return exp2f(x);
#endif
}

__device__ __forceinline__ float fast_log2(float x) {
#if __has_builtin(__builtin_amdgcn_logf)
  return __builtin_amdgcn_logf(x);
#else
  return __log2f(x);
#endif
}

__device__ __forceinline__ float fast_rcp(float x) {
#if __has_builtin(__builtin_amdgcn_rcpf)
  return __builtin_amdgcn_rcpf(x);
#else
  return 1.0f / x;
#endif
}

__device__ __forceinline__ f2 f2fma(f2 a, f2 b, f2 c) {
#if __has_builtin(__builtin_elementwise_fma)
  return __builtin_elementwise_fma(a, b, c);
#else
  f2 r; r[0] = fmaf(a[0], b[0], c[0]); r[1] = fmaf(a[1], b[1], c[1]); return r;
#endif
}

template <int CTRL>
__device__ __forceinline__ float dpp_movf(float x) {
  return __int_as_float(
      __builtin_amdgcn_update_dpp(0, __float_as_int(x), CTRL, 0xf, 0xf, true));
}

__device__ __forceinline__ uint2_ev pl16_swap(unsigned a, unsigned b) {
  return __builtin_amdgcn_permlane16_swap(a, b, false, false);
}

// 32-lane half-group reductions (verified construction, R1-R8).
__device__ __forceinline__ float hgroup_max(float x) {
  x = fmaxf(x, dpp_movf<0x121>(x));
  x = fmaxf(x, dpp_movf<0x122>(x));
  x = fmaxf(x, dpp_movf<0x124>(x));
  x = fmaxf(x, dpp_movf<0x128>(x));
  uint2_ev r = pl16_swap(__float_as_uint(x), __float_as_uint(x));
  return fmaxf(__uint_as_float(r[0]), __uint_as_float(r[1]));
}

__device__ __forceinline__ float hgroup_sum(float x) {
  x += dpp_movf<0x121>(x);
  x += dpp_movf<0x122>(x);
  x += dpp_movf<0x124>(x);
  x += dpp_movf<0x128>(x);
  uint2_ev r = pl16_swap(__float_as_uint(x), __float_as_uint(x));
  return __uint_as_float(r[0]) + __uint_as_float(r[1]);
}

// Combine lane l with lane l^32 (verified R1-R3 construction).
__device__ __forceinline__ float x32_sum(float x) {
#if __has_builtin(__builtin_amdgcn_permlane32_swap)
  uint2_ev r = __builtin_amdgcn_permlane32_swap(
      (unsigned)__float_as_int(x), (unsigned)__float_as_int(x), false, false);
  return __int_as_float((int)r[0]) + __int_as_float((int)r[1]);
#else
  return x + __shfl_xor(x, 32, 64);
#endif
}

// Gumbel noise + temperature scaling, output in log2 domain.
__device__ __forceinline__ float gumbel_la(float p, float uv, float scale) {
  float lnu = fast_log2(uv + 1e-20f) * 0.69314718056f;
  float g = fast_log2(1e-20f - lnu) * (-0.0069314718056f);
  return (p + g) * scale;
}

__global__ __launch_bounds__(1024)
__attribute__((amdgpu_waves_per_eu(4, 4)))
void lp_sinkhorn_kernel(
    const float* __restrict__ plw, const float* __restrict__ uin,
    const int* __restrict__ itp, float* __restrict__ out) {
  const int k = blockIdx.x;
  const int t = threadIdx.x;
  const int br = t >> 5;   // 0..31 : half-wave row-group (8 rows each)
  const int bc = t & 31;   // 0..31 : col-group (8 cols each)
  const int wv = t >> 6;   // wave 0..15
  const int lane = t & 63;

  // Wave partials: pw[w][32p+bc] (f2) = 16-row partial of column pair
  // (8bc+2p, 8bc+2p+1), rows 16w..16w+15. f2 stride 132 = 264 floats
  // (bank rotate 8/row) -> tree reads and writes are <=2-way (free).
  __shared__ f2 pw[16][132];
  __shared__ f2 colvp[132];        // rcp'd colsums, f2 slot 32p+bc
  float* pwF = (float*)pw;         // row stride = 264 floats
  float* colvF = (float*)colvp;    // scalar col slot s = 64p+2bc+h

  const int ts = t >> 2;   // tree: scalar col slot (0..255)
  const int tq = t & 3;    // tree: quad index (reads rows 4m+tq)

  // ---- schedule parameters from `iterations` (uniform) ----
  double frac = (double)itp[0] * 1e-5;
  frac = frac < 0.0 ? 0.0 : (frac > 1.0 ? 1.0 : frac);
  const int n_iters = (int)(20.0 + frac * 130.0);
  const float tauf = (float)exp2((-3.0 - 4.0 * frac) * 3.3219280948873623);
  const float scale = (float)(1.4426950408889634 / (double)tauf);

  f2 la[8][4];

  // ---- load + gumbel + scale (log2 domain) ----
  const float4* p4 = (const float4*)plw + k * 16384;
  const float4* u4 = (const float4*)uin + k * 16384;
#pragma unroll
  for (int i = 0; i < 8; ++i) {
    const int ridx = ((br << 3) + i) * 64 + (bc << 1);
    float4 p0 = p4[ridx];
    float4 p1 = p4[ridx + 1];
    float4 v0 = u4[ridx];
    float4 v1 = u4[ridx + 1];
    la[i][0] = f2{gumbel_la(p0.x, v0.x, scale), gumbel_la(p0.y, v0.y, scale)};
    la[i][1] = f2{gumbel_la(p0.z, v0.z, scale), gumbel_la(p0.w, v0.w, scale)};
    la[i][2] = f2{gumbel_la(p1.x, v1.x, scale), gumbel_la(p1.y, v1.y, scale)};
    la[i][3] = f2{gumbel_la(p1.z, v1.z, scale), gumbel_la(p1.w, v1.w, scale)};
  }

  // ---- row pass #1 (log domain, in-wave) fused convert to linear ----
  // After this, la is linear with rowsums == 1 (entries <= 1).
#pragma unroll
  for (int i = 0; i < 8; ++i) {
    float m = fmaxf(la[i][0][0], la[i][0][1]);
#pragma unroll
    for (int p = 1; p < 4; ++p) m = fmaxf(m, fmaxf(la[i][p][0], la[i][p][1]));
    m = hgroup_max(m);
    float s = 0.f;
#pragma unroll
    for (int p = 0; p < 4; ++p) {
      la[i][p] = f2{fast_exp2(la[i][p][0] - m), fast_exp2(la[i][p][1] - m)};
      s += la[i][p][0] + la[i][p][1];
    }
    s = hgroup_sum(s);
    const float r = fast_rcp(s);
#pragma unroll
    for (int p = 0; p < 4; ++p) la[i][p] *= f2{r, r};
  }

  float u[8] = {1.f, 1.f, 1.f, 1.f, 1.f, 1.f, 1.f, 1.f};

  // ---- epoch 1: col sums of row-normalized A (u == 1) ----
  {
    f2 cs[4];
#pragma unroll
    for (int p = 0; p < 4; ++p) cs[p] = la[0][p];
#pragma unroll
    for (int i = 1; i < 8; ++i)
#pragma unroll
      for (int p = 0; p < 4; ++p) cs[p] += la[i][p];
    // wave-combine (rows 16w..16w+15) and write from lanes < 32
#pragma unroll
    for (int p = 0; p < 4; ++p)
      cs[p] = f2{x32_sum(cs[p][0]), x32_sum(cs[p][1])};
    if (lane < 32) {
#pragma unroll
      for (int p = 0; p < 4; ++p) pw[wv][32 * p + bc] = cs[p];
    }
    __syncthreads();
    {  // shallow tree: 4 threads/col, 4 reads, quad-DPP finish
      float v = pwF[tq * 264 + ts];
#pragma unroll
      for (int m = 1; m < 4; ++m) v += pwF[(4 * m + tq) * 264 + ts];
      v += dpp_movf<0xB1>(v);  // quad xor1
      v += dpp_movf<0x4E>(v);  // quad xor2
      if (tq == 0) colvF[ts] = fast_rcp(v);
    }
    __syncthreads();
  }

  // ---- epochs 2..n: u = rcp(A v); col partials of a*u; tree -> v ----
  for (int it = 2; it <= n_iters; ++it) {
    f2 v2[4];
#pragma unroll
    for (int p = 0; p < 4; ++p) v2[p] = colvp[32 * p + bc];

    // phase A: row dots (packed) + in-wave reduce
#pragma unroll
    for (int i = 0; i < 8; ++i) {
      f2 a01 = la[i][0] * v2[0];
      a01 = f2fma(la[i][1], v2[1], a01);
      f2 a23 = la[i][2] * v2[2];
      a23 = f2fma(la[i][3], v2[3], a23);
      f2 acc = a01 + a23;
      u[i] = fast_rcp(hgroup_sum(acc[0] + acc[1]));
    }

    // phase B: col partials (packed fma) over this thread's 8 rows
    f2 cs[4];
    {
      const f2 ub0 = f2{u[0], u[0]};
#pragma unroll
      for (int p = 0; p < 4; ++p) cs[p] = la[0][p] * ub0;
    }
#pragma unroll
    for (int i = 1; i < 8; ++i) {
      const f2 ub = f2{u[i], u[i]};
#pragma unroll
      for (int p = 0; p < 4; ++p) cs[p] = f2fma(la[i][p], ub, cs[p]);
    }
    // wave-combine + write from lanes < 32
#pragma unroll
    for (int p = 0; p < 4; ++p)
      cs[p] = f2{x32_sum(cs[p][0]), x32_sum(cs[p][1])};
    if (lane < 32) {
#pragma unroll
      for (int p = 0; p < 4; ++p) pw[wv][32 * p + bc] = cs[p];
    }
    __syncthreads();

    {  // shallow tree -> colv = rcp(colsum)
      float v = pwF[tq * 264 + ts];
#pragma unroll
      for (int m = 1; m < 4; ++m) v += pwF[(4 * m + tq) * 264 + ts];
      v += dpp_movf<0xB1>(v);
      v += dpp_movf<0x4E>(v);
      if (tq == 0) colvF[ts] = fast_rcp(v);
    }
    __syncthreads();
  }

  // ---- epilogue: v = last colv; out = a_ij * u_i * v_j ----
  f2 v2[4];
#pragma unroll
  for (int p = 0; p < 4; ++p) v2[p] = colvp[32 * p + bc];

  float4* o4 = (float4*)out + k * 16384;
#pragma unroll
  for (int i = 0; i < 8; ++i) {
    const int ridx = ((br << 3) + i) * 64 + (bc << 1);
    const f2 ub = f2{u[i], u[i]};
    f2 r0 = (la[i][0] * ub) * v2[0];
    f2 r1 = (la[i][1] * ub) * v2[1];
    f2 r2 = (la[i][2] * ub) * v2[2];
    f2 r3 = (la[i][3] * ub) * v2[3];
    float4 a, b;
    a.x = r0[0]; a.y = r0[1]; a.z = r1[0]; a.w = r1[1];
    b.x = r2[0]; b.y = r2[1]; b.z = r3[0]; b.w = r3[1];
    o4[ridx] = a;
    o4[ridx + 1] = b;
  }
}

extern "C" void kernel_launch(void* const* d_in, const int* in_sizes, int n_in,
                              void* d_out, int out_size, void* d_ws,
                              size_t ws_size, hipStream_t stream) {
  const float* plw = (const float*)d_in[0];
  const float* u = (const float*)d_in[1];
  const int* iters = (const int*)d_in[2];
  float* out = (float*)d_out;
  (void)in_sizes; (void)n_in; (void)out_size; (void)d_ws; (void)ws_size;
  lp_sinkhorn_kernel<<<dim3(KMAT), dim3(1024), 0, stream>>>(plw, u, iters, out);
}